// Round 6
// baseline (782.135 us; speedup 1.0000x reference)
//
#include <hip/hip_runtime.h>
#include <hip/hip_bf16.h>

#define NN 20000
#define NE 300000
#define HIDN 128
#define NLAY 4
#define NTILES ((NE + 63) / 64)

typedef short short8 __attribute__((ext_vector_type(8)));
typedef short short4v __attribute__((ext_vector_type(4)));
typedef float f32x4 __attribute__((ext_vector_type(4)));
typedef unsigned short us16;
typedef unsigned int u32;

__device__ __forceinline__ float lrelu(float x){ return x >= 0.f ? x : 0.2f * x; }
__device__ __forceinline__ float b2f(us16 u){ return __uint_as_float(((u32)u) << 16); }
__device__ __forceinline__ us16 f2b(float f){
    u32 u = __float_as_uint(f);
    u += 0x7FFFu + ((u >> 16) & 1u);
    return (us16)(u >> 16);
}
__device__ __forceinline__ float rawf(const void* p, size_t i, int dt){
    return dt ? b2f(((const us16*)p)[i]) : ((const float*)p)[i];
}
// staging swizzle (u32 granularity) for k_gatwx
__device__ __forceinline__ int swzi(int i){
    return (i & ~15) | ((i & 15) ^ (((i >> 5) & 3) << 2));
}

__device__ __forceinline__ void ln_stats_128(float v, volatile float* red, float& mean, float& inv){
    float s = v, s2 = v * v;
#pragma unroll
    for (int m = 32; m >= 1; m >>= 1){ s += __shfl_xor(s, m, 64); s2 += __shfl_xor(s2, m, 64); }
    int w = threadIdx.x >> 6;
    if ((threadIdx.x & 63) == 0){ red[w*2] = s; red[w*2+1] = s2; }
    __syncthreads();
    float ts = red[0] + red[2], ts2 = red[1] + red[3];
    mean = ts * (1.f/128.f);
    float var = ts2 * (1.f/128.f) - mean * mean;
    inv = rsqrtf(var + 1e-5f);
    __syncthreads();
}

// ---------------- dtype detect + convert ----------------
__global__ void k_detect(const u32* __restrict__ ne_g, int* __restrict__ flag){
    flag[0] = (ne_g[0] == 0x3F803F80u) ? 1 : 0;
}

struct ConvEnt { const void* s; float* d; int n; int pad; };
struct ConvTab { ConvEnt c[28]; int cnt; int pad[3]; };

__global__ void k_convert_all(ConvTab tab, const int* __restrict__ flag){
    int ti = blockIdx.y;
    if (ti >= tab.cnt) return;
    const void* s = tab.c[ti].s;
    float* d = tab.c[ti].d;
    int n = tab.c[ti].n;
    int dt = flag[0];
    for (int i = blockIdx.x*blockDim.x + threadIdx.x; i < n; i += gridDim.x*blockDim.x)
        d[i] = rawf(s, i, dt);
}

// ---------------- bf16 weight prep ----------------
// w1t[L][128][256] = ecw1^T ; w2t[L][128][128] = ecw2^T ; gws slice-major for gatwx
#define W1T (128*256)
#define W2T (128*128)
#define GWSZ (4*128*32)
#define PER_L (W1T + W2T + GWSZ)
#define PTOT2 (NLAY*PER_L)
__global__ void k_prepw(const void* __restrict__ ecw1r, const void* __restrict__ ecw2r,
                        const void* __restrict__ gatwr, const int* __restrict__ flag,
                        us16* __restrict__ w1t, us16* __restrict__ w2t, us16* __restrict__ gws){
    int id = blockIdx.x*blockDim.x + threadIdx.x;
    if (id >= PTOT2) return;
    int dt = flag[0];
    int L = id / PER_L, r = id % PER_L;
    if (r < W1T){
        int n = r >> 8, k = r & 255;
        w1t[(size_t)L*W1T + r] = f2b(rawf(ecw1r, (size_t)L*32768 + (size_t)k*128 + n, dt));
    } else if (r < W1T + W2T){
        int rr = r - W1T; int n = rr >> 7, k = rr & 127;
        w2t[(size_t)L*W2T + rr] = f2b(rawf(ecw2r, (size_t)L*16384 + (size_t)k*128 + n, dt));
    } else {
        int rr = r - W1T - W2T;
        int kk = rr >> 12, rem = rr & 4095, n = rem >> 5, ks = rem & 31;
        int k = kk*32 + ks;
        gws[(size_t)L*GWSZ + rr] = f2b(rawf(gatwr, (size_t)L*16384 + (size_t)k*128 + n, dt));
    }
}

// ---------------- CSR build ----------------
__global__ void k_hist(const int* __restrict__ dstI, int* __restrict__ cnt){
    int e = blockIdx.x*blockDim.x + threadIdx.x;
    if (e < NE) atomicAdd(&cnt[dstI[e]], 1);
}
__global__ void k_scan(const int* __restrict__ cnt, int* __restrict__ rowptr){
    __shared__ int ps[256];
    int t = threadIdx.x;
    int chunk = (NN + 255) / 256;
    int beg = t*chunk, end = beg + chunk; if (end > NN) end = NN;
    int s = 0;
    for (int i = beg; i < end; ++i) s += cnt[i];
    ps[t] = s; __syncthreads();
    int off = 0;
    for (int i = 0; i < t; ++i) off += ps[i];
    int run = off;
    for (int i = beg; i < end; ++i){ rowptr[i] = run; run += cnt[i]; }
    if (t == 255) rowptr[NN] = run;
}
__global__ void k_csrfill(const int* __restrict__ srcI, const int* __restrict__ dstI,
                          int* __restrict__ cur, int* __restrict__ perm,
                          int* __restrict__ csr_src){
    int e = blockIdx.x*blockDim.x + threadIdx.x;
    if (e < NE){
        int p = atomicAdd(&cur[dstI[e]], 1);
        perm[e] = p;
        csr_src[p] = srcI[e];
    }
}

// ---------------- node encoder ----------------
__global__ void k_nodeenc(const float* __restrict__ xf, const float* __restrict__ w,
                          const float* __restrict__ b, const float* __restrict__ g,
                          const float* __restrict__ beta, float* __restrict__ h,
                          us16* __restrict__ xb){
    __shared__ float red[4];
    int n = blockIdx.x, t = threadIdx.x;
    float acc = b[t];
#pragma unroll
    for (int k = 0; k < 4; ++k) acc = fmaf(xf[n*4+k], w[k*HIDN+t], acc);
    acc = lrelu(acc);
    float mean, inv; ln_stats_128(acc, red, mean, inv);
    float o = (acc-mean)*inv*g[t] + beta[t];
    h[(size_t)n*HIDN+t] = o;
    xb[(size_t)n*HIDN+t] = f2b(o);
}

// ---------------- per-node gate dots: gd = wa[0:128].x + ba ; gs = wa[128:256].x ----------------
__global__ void k_predot(const float* __restrict__ x, const float* __restrict__ wa,
                         const float* __restrict__ baP, float* __restrict__ gd,
                         float* __restrict__ gs){
    int wv = threadIdx.x >> 6, l = threadIdx.x & 63;
    int n = blockIdx.x*4 + wv;
    if (n >= NN) return;
    float2 xv = *(const float2*)(x + (size_t)n*HIDN + 2*l);
    float pd = xv.x*wa[2*l]     + xv.y*wa[2*l+1];
    float ps = xv.x*wa[128+2*l] + xv.y*wa[129+2*l];
#pragma unroll
    for (int mk = 32; mk >= 1; mk >>= 1){ pd += __shfl_xor(pd, mk, 64); ps += __shfl_xor(ps, mk, 64); }
    if (l == 0){ gd[n] = pd + baP[0]; gs[n] = ps; }
}

// ---------------- EdgeConv: weights-in-registers, grid-stride 64-edge tiles ----------------
__global__ __launch_bounds__(256, 2) void k_edgeconv_mfma(
    const us16* __restrict__ xb, const int* __restrict__ srcI, const int* __restrict__ dstI,
    const us16* __restrict__ w1t, const us16* __restrict__ w2t,
    const float* __restrict__ b1, const float* __restrict__ lng, const float* __restrict__ lnb,
    const float* __restrict__ b2, const float* __restrict__ gd, const float* __restrict__ gs,
    const int* __restrict__ perm, us16* __restrict__ msg)
{
    __shared__ __align__(16) us16 m1s[64*128];   // 16 KB
    __shared__ __align__(16) us16 m2s[64*128];   // 16 KB
    __shared__ float2 red[4*4*16];               // [w][g][lr]
    __shared__ float2 mi[4*16];                  // [et][lr] {mean, inv}
    int t = threadIdx.x;
    int wv = t >> 6, lane = t & 63, g = lane >> 4, lr = lane & 15;

    // persistent weight A-fragments: wave wv owns channels [32wv, 32wv+32)
    short8 fr1[2][8], fr2[2][4];
#pragma unroll
    for (int nt = 0; nt < 2; ++nt){
        int chan = wv*32 + nt*16 + lr;
#pragma unroll
        for (int kk = 0; kk < 8; ++kk)
            fr1[nt][kk] = *(const short8*)(w1t + chan*256 + kk*32 + g*8);
#pragma unroll
        for (int kk = 0; kk < 4; ++kk)
            fr2[nt][kk] = *(const short8*)(w2t + chan*128 + kk*32 + g*8);
    }
    // per-lane channel constants (chan = wv*32 + nt*16 + g*4 + r)
    float b1v[8], lngv[8], lnbv[8], b2v[8];
#pragma unroll
    for (int nt = 0; nt < 2; ++nt)
#pragma unroll
        for (int r = 0; r < 4; ++r){
            int c = wv*32 + nt*16 + g*4 + r;
            b1v[nt*4+r] = b1[c]; lngv[nt*4+r] = lng[c]; lnbv[nt*4+r] = lnb[c]; b2v[nt*4+r] = b2[c];
        }
    int swzl = (lr & 7) << 3;

    for (int tile = blockIdx.x; tile < NTILES; tile += gridDim.x){
        int e0 = tile * 64;
        u32 offd[4], offs[4];
#pragma unroll
        for (int et = 0; et < 4; ++et){
            int e = e0 + et*16 + lr; if (e >= NE) e = NE - 1;
            offd[et] = (u32)dstI[e] * HIDN;
            offs[et] = (u32)srcI[e] * HIDN;
        }

        // ---- GEMM1: C[chan][edge] ----
        f32x4 a1[2][4];
#pragma unroll
        for (int nt = 0; nt < 2; ++nt)
#pragma unroll
            for (int et = 0; et < 4; ++et) a1[nt][et] = (f32x4)(0.f);
#pragma unroll
        for (int et = 0; et < 4; ++et){
            short8 bF[8];
#pragma unroll
            for (int kk = 0; kk < 8; ++kk)
                bF[kk] = *(const short8*)(xb + ((kk < 4) ? offd[et] : offs[et]) + (kk&3)*32 + g*8);
#pragma unroll
            for (int kk = 0; kk < 8; ++kk){
                a1[0][et] = __builtin_amdgcn_mfma_f32_16x16x32_bf16(fr1[0][kk], bF[kk], a1[0][et], 0, 0, 0);
                a1[1][et] = __builtin_amdgcn_mfma_f32_16x16x32_bf16(fr1[1][kk], bF[kk], a1[1][et], 0, 0, 0);
            }
        }

        // ---- per-edge LN stats (cross-wave over channels) ----
        float sE[4] = {0,0,0,0}, qE[4] = {0,0,0,0};
#pragma unroll
        for (int nt = 0; nt < 2; ++nt)
#pragma unroll
            for (int r = 0; r < 4; ++r)
#pragma unroll
                for (int et = 0; et < 4; ++et){
                    float v = lrelu(a1[nt][et][r] + b1v[nt*4+r]);
                    sE[et] += v; qE[et] += v*v;
                }
#pragma unroll
        for (int mk = 16; mk <= 32; mk <<= 1)
#pragma unroll
            for (int et = 0; et < 4; ++et){ sE[et] += __shfl_xor(sE[et], mk, 64); qE[et] += __shfl_xor(qE[et], mk, 64); }
        red[(wv*4 + g)*16 + lr] = make_float2(sE[g], qE[g]);
        __syncthreads();
        {
            float ts = 0.f, ts2 = 0.f;
#pragma unroll
            for (int w = 0; w < 4; ++w){ float2 v = red[(w*4 + g)*16 + lr]; ts += v.x; ts2 += v.y; }
            float mean = ts * (1.f/128.f);
            float var  = ts2 * (1.f/128.f) - mean*mean;
            mi[g*16 + lr] = make_float2(mean, rsqrtf(var + 1e-5f));
        }
        __syncthreads();
        float2 miv[4];
#pragma unroll
        for (int et = 0; et < 4; ++et) miv[et] = mi[et*16 + lr];

        // ---- normalize + write m1s[edge][chan^swz] ----
#pragma unroll
        for (int et = 0; et < 4; ++et){
            int edge = et*16 + lr;
#pragma unroll
            for (int nt = 0; nt < 2; ++nt){
                short4v pk;
#pragma unroll
                for (int r = 0; r < 4; ++r){
                    float v = lrelu(a1[nt][et][r] + b1v[nt*4+r]);
                    v = (v - miv[et].x)*miv[et].y*lngv[nt*4+r] + lnbv[nt*4+r];
                    pk[r] = (short)f2b(v);
                }
                int c0 = wv*32 + nt*16 + g*4;
                *(short4v*)(m1s + edge*128 + (c0 ^ swzl)) = pk;
            }
        }
        __syncthreads();

        // ---- GEMM2 ----
        f32x4 a2[2][4];
#pragma unroll
        for (int nt = 0; nt < 2; ++nt)
#pragma unroll
            for (int et = 0; et < 4; ++et) a2[nt][et] = (f32x4)(0.f);
#pragma unroll
        for (int et = 0; et < 4; ++et){
            int edge = et*16 + lr;
#pragma unroll
            for (int kk = 0; kk < 4; ++kk){
                short8 bF = *(const short8*)(m1s + edge*128 + ((kk*32 + g*8) ^ swzl));
                a2[0][et] = __builtin_amdgcn_mfma_f32_16x16x32_bf16(fr2[0][kk], bF, a2[0][et], 0, 0, 0);
                a2[1][et] = __builtin_amdgcn_mfma_f32_16x16x32_bf16(fr2[1][kk], bF, a2[1][et], 0, 0, 0);
            }
        }

        // ---- epilogue: bias+lrelu -> m2s ----
#pragma unroll
        for (int et = 0; et < 4; ++et){
            int edge = et*16 + lr;
#pragma unroll
            for (int nt = 0; nt < 2; ++nt){
                short4v pk;
#pragma unroll
                for (int r = 0; r < 4; ++r)
                    pk[r] = (short)f2b(lrelu(a2[nt][et][r] + b2v[nt*4+r]));
                int c0 = wv*32 + nt*16 + g*4;
                *(short4v*)(m2s + edge*128 + (c0 ^ swzl)) = pk;
            }
        }
        __syncthreads();

        // ---- gated, permuted row write ----
        {
            int row = t >> 2, q4 = t & 3;
            int e = e0 + row;
            if (e < NE){
                float z = gd[dstI[e]] + gs[srcI[e]];
                float gate = 1.f / (1.f + __expf(-z));
                size_t ob = (size_t)perm[e] * HIDN;
                int swz = (row & 7) << 3;
#pragma unroll
                for (int j = 0; j < 4; ++j){
                    int col = q4*32 + j*8;
                    short8 v = *(const short8*)(m2s + row*128 + (col ^ swz));
                    short8 o;
#pragma unroll
                    for (int q = 0; q < 8; ++q)
                        o[q] = (short)f2b(b2f((us16)v[q]) * gate);
                    *(short8*)(msg + ob + col) = o;
                }
            }
        }
        __syncthreads();
    }
}

// ---------------- GAT wx (MFMA, swizzled dbuf B) + fused head dots + bf16 out ----------------
__global__ __launch_bounds__(256, 4) void k_gatwx(
    const us16* __restrict__ xb, const us16* __restrict__ gws,
    const float* __restrict__ aws, const float* __restrict__ awd,
    us16* __restrict__ wxb, float* __restrict__ asrc, float* __restrict__ adst)
{
    __shared__ __align__(16) us16 sbuf[64*128];  // 16 KB
    __shared__ __align__(16) u32 bsl[2][2048];   // 16 KB
    int t = threadIdx.x;
    int wv = t >> 6, lane = t & 63, g = lane >> 4, lr = lane & 15;
    int n0 = blockIdx.x * 64;

    int rn = n0 + wv*16 + lr; if (rn >= NN) rn = NN - 1;
    short8 aN[4];
#pragma unroll
    for (int kk = 0; kk < 4; ++kk)
        aN[kk] = *(const short8*)(xb + (size_t)rn*HIDN + kk*32 + g*8);

    const u32* gwu = (const u32*)gws;
    u32 rS[8];
#pragma unroll
    for (int q = 0; q < 8; ++q) rS[q] = gwu[t + 256*q];
#pragma unroll
    for (int q = 0; q < 8; ++q) bsl[0][swzi(t + 256*q)] = rS[q];
#pragma unroll
    for (int q = 0; q < 8; ++q) rS[q] = gwu[2048 + t + 256*q];
    __syncthreads();

    f32x4 acc[8];
#pragma unroll
    for (int i = 0; i < 8; ++i) acc[i] = (f32x4)(0.f);
#pragma unroll
    for (int kk = 0; kk < 4; ++kk){
        const us16* bp = (const us16*)bsl[kk & 1];
#pragma unroll
        for (int nt = 0; nt < 8; ++nt){
            int row = nt*16 + lr;
            short8 bF = *(const short8*)(bp + row*32 + (g*8 ^ (((row>>1)&3)<<3)));
            acc[nt] = __builtin_amdgcn_mfma_f32_16x16x32_bf16(aN[kk], bF, acc[nt], 0, 0, 0);
        }
        if (kk < 3){
#pragma unroll
            for (int q = 0; q < 8; ++q) bsl[(kk+1)&1][swzi(t + 256*q)] = rS[q];
            if (kk < 2){
#pragma unroll
                for (int q = 0; q < 8; ++q) rS[q] = gwu[(kk+2)*2048 + t + 256*q];
            }
        }
        __syncthreads();
    }

    float awsv[8], awdv[8];
#pragma unroll
    for (int nt = 0; nt < 8; ++nt){ awsv[nt] = aws[nt*16 + lr]; awdv[nt] = awd[nt*16 + lr]; }
    float sa[4][4], sd[4][4];
#pragma unroll
    for (int r = 0; r < 4; ++r)
#pragma unroll
        for (int h = 0; h < 4; ++h){
            sa[r][h] = acc[2*h][r]*awsv[2*h] + acc[2*h+1][r]*awsv[2*h+1];
            sd[r][h] = acc[2*h][r]*awdv[2*h] + acc[2*h+1][r]*awdv[2*h+1];
        }
#pragma unroll
    for (int mk = 8; mk >= 1; mk >>= 1)
#pragma unroll
        for (int r = 0; r < 4; ++r)
#pragma unroll
            for (int h = 0; h < 4; ++h){
                sa[r][h] += __shfl_xor(sa[r][h], mk, 64);
                sd[r][h] += __shfl_xor(sd[r][h], mk, 64);
            }
    if (lr == 0){
#pragma unroll
        for (int r = 0; r < 4; ++r){
            int n = n0 + wv*16 + g*4 + r;
            if (n < NN){
                *(float4*)(asrc + (size_t)n*4) = make_float4(sa[r][0], sa[r][1], sa[r][2], sa[r][3]);
                *(float4*)(adst + (size_t)n*4) = make_float4(sd[r][0], sd[r][1], sd[r][2], sd[r][3]);
            }
        }
    }

#pragma unroll
    for (int r = 0; r < 4; ++r){
        int row = wv*16 + g*4 + r;
        int swz = (row & 7) << 3;
#pragma unroll
        for (int nt = 0; nt < 8; ++nt)
            sbuf[row*128 + ((nt*16 + lr) ^ swz)] = f2b(acc[nt][r]);
    }
    __syncthreads();
    {
        int row = t >> 2, ch = t & 3;
        int n = n0 + row;
        if (n < NN){
            int swz = (row & 7) << 3;
#pragma unroll
            for (int q = 0; q < 4; ++q){
                int col = ch*32 + q*8;
                *(short8*)(wxb + (size_t)n*HIDN + col) = *(const short8*)(sbuf + row*128 + (col ^ swz));
            }
        }
    }
}

// ---------------- fused node update ----------------
__global__ __launch_bounds__(256, 8) void k_node_update(
    const int* __restrict__ rowptr, const int* __restrict__ csr_src,
    const us16* __restrict__ msg, const us16* __restrict__ wxb,
    const float* __restrict__ asrc, const float* __restrict__ adst,
    const float* __restrict__ xc, const float* __restrict__ gbias,
    const float* __restrict__ lng, const float* __restrict__ lnb,
    float* __restrict__ xout, us16* __restrict__ xbout, int maxmode)
{
    int wv = threadIdx.x >> 6, l = threadIdx.x & 63;
    int n = blockIdx.x*4 + wv;
    if (n >= NN) return;
    int c0 = 2*l, c1 = 2*l + 1;
    int h = l >> 4;

    int b = rowptr[n], en = rowptr[n+1];
    int deg = en - b;

    float adst_h = adst[(size_t)n*4 + h];
    float pself = __expf(fminf(lrelu(asrc[(size_t)n*4 + h] + adst_h), 80.f));
    u32 wq = *(const u32*)(wxb + (size_t)n*HIDN + c0);
    float att0 = pself * b2f((us16)(wq & 0xFFFFu));
    float att1 = pself * b2f((us16)(wq >> 16));
    float den = pself;

    float agg0, agg1;
    if (maxmode){ agg0 = agg1 = -3.0e38f; } else { agg0 = agg1 = 0.f; }

    for (int i = b; i < en; ++i){
        int s = csr_src[i];
        u32 mq = *(const u32*)(msg + (size_t)i*HIDN + c0);
        float m0 = b2f((us16)(mq & 0xFFFFu)), m1 = b2f((us16)(mq >> 16));
        if (maxmode){ agg0 = fmaxf(agg0, m0); agg1 = fmaxf(agg1, m1); }
        else        { agg0 += m0; agg1 += m1; }
        float p = __expf(fminf(lrelu(asrc[(size_t)s*4 + h] + adst_h), 80.f));
        u32 wq2 = *(const u32*)(wxb + (size_t)s*HIDN + c0);
        att0 = fmaf(p, b2f((us16)(wq2 & 0xFFFFu)), att0);
        att1 = fmaf(p, b2f((us16)(wq2 >> 16)), att1);
        den += p;
    }
    float rden = 1.f / den;
    att0 *= rden; att1 *= rden;
    if (maxmode){ if (deg == 0){ agg0 = 0.f; agg1 = 0.f; } }
    else { float rd = 1.f / fmaxf((float)deg, 1.f); agg0 *= rd; agg1 *= rd; }

    float2 xcv = *(const float2*)(xc + (size_t)n*HIDN + c0);
    float s0 = xcv.x + agg0 + att0 + gbias[c0];
    float s1 = xcv.y + agg1 + att1 + gbias[c1];

    float ss = s0 + s1, ss2 = s0*s0 + s1*s1;
#pragma unroll
    for (int mk = 32; mk >= 1; mk >>= 1){ ss += __shfl_xor(ss, mk, 64); ss2 += __shfl_xor(ss2, mk, 64); }
    float mean = ss * (1.f/128.f);
    float var  = ss2 * (1.f/128.f) - mean*mean;
    float inv  = rsqrtf(var + 1e-5f);
    float o0 = lrelu((s0-mean)*inv*lng[c0] + lnb[c0]);
    float o1 = lrelu((s1-mean)*inv*lng[c1] + lnb[c1]);
    *(float2*)(xout + (size_t)n*HIDN + c0) = make_float2(o0, o1);
    u32 pk = (u32)f2b(o0) | ((u32)f2b(o1) << 16);
    *(u32*)(xbout + (size_t)n*HIDN + c0) = pk;
}

// ---------------- dueling heads ----------------
__global__ void k_heads(const float* __restrict__ xc,
                        const float* __restrict__ aw1, const float* __restrict__ ab1,
                        const float* __restrict__ ag,  const float* __restrict__ abeta,
                        const float* __restrict__ aw2, const float* __restrict__ ab2,
                        const float* __restrict__ vw1, const float* __restrict__ vb1,
                        const float* __restrict__ vg,  const float* __restrict__ vbeta,
                        const float* __restrict__ vw2, const float* __restrict__ vb2,
                        void* __restrict__ dout, const int* __restrict__ flag){
    __shared__ float red[4];
    __shared__ float ts[128], u1[128], aout[10];
    int t = threadIdx.x;
    ts[t] = xc[t];
    __syncthreads();
    float acc = ab1[t];
    for (int k = 0; k < 128; ++k) acc = fmaf(ts[k], aw1[k*HIDN+t], acc);
    acc = lrelu(acc);
    float mean, inv; ln_stats_128(acc, red, mean, inv);
    u1[t] = (acc-mean)*inv*ag[t] + abeta[t];
    __syncthreads();
    if (t < 10){
        float a = ab2[t];
        for (int k = 0; k < 128; ++k) a = fmaf(u1[k], aw2[k*10+t], a);
        aout[t] = a;
    }
    __syncthreads();
    float accv = vb1[t];
    for (int k = 0; k < 128; ++k) accv = fmaf(ts[k], vw1[k*HIDN+t], accv);
    accv = lrelu(accv);
    float meanv, invv; ln_stats_128(accv, red, meanv, invv);
    float v1 = (accv-meanv)*invv*vg[t] + vbeta[t];
    float pv = v1 * vw2[t];
#pragma unroll
    for (int m = 32; m >= 1; m >>= 1) pv += __shfl_xor(pv, m, 64);
    if ((t & 63) == 0) red[t >> 6] = pv;
    __syncthreads();
    if (t == 0){
        float v = red[0] + red[1] + vb2[0];
        float am = 0.f;
        for (int j = 0; j < 10; ++j) am += aout[j];
        am *= 0.1f;
        int dt = flag[0];
        for (int j = 0; j < 11; ++j){
            float val = (j < 10) ? (v + aout[j] - am) : v;
            if (dt) ((__hip_bfloat16*)dout)[j] = __float2bfloat16(val);
            else    ((float*)dout)[j] = val;
        }
    }
}

extern "C" void kernel_launch(void* const* d_in, const int* in_sizes, int n_in,
                              void* d_out, int out_size, void* d_ws, size_t ws_size,
                              hipStream_t stream)
{
    float* base = (float*)d_ws;
    size_t off = 0;
    auto A = [&](size_t n)->float*{ float* p = base + off; off += (n + 63) & ~(size_t)63; return p; };

    int*   flag   = (int*)A(64);
    float* xf     = A((size_t)NN*4);
    float* new_w  = A(4*HIDN); float* neb = A(HIDN); float* neg_ = A(HIDN); float* nebeta = A(HIDN);
    float* ecb1   = A(NLAY*HIDN);
    float* eclng  = A(NLAY*HIDN); float* eclnb = A(NLAY*HIDN);
    float* ecb2   = A(NLAY*HIDN);
    float* ecwa   = A(NLAY*256);  float* ecba = A(NLAY);
    float* gasrc  = A(NLAY*HIDN); float* gadst = A(NLAY*HIDN); float* gbias = A(NLAY*HIDN);
    float* lng    = A(NLAY*HIDN); float* lnb = A(NLAY*HIDN);
    float* aw1    = A(HIDN*HIDN); float* ab1 = A(HIDN); float* ag = A(HIDN); float* abeta = A(HIDN);
    float* aw2    = A(HIDN*10);   float* ab2 = A(10);
    float* vw1    = A(HIDN*HIDN); float* vb1 = A(HIDN); float* vg = A(HIDN); float* vbeta = A(HIDN);
    float* vw2    = A(HIDN);      float* vb2 = A(1);
    // bf16 weights
    us16* w1t = (us16*)A((size_t)NLAY*W1T/2);
    us16* w2t = (us16*)A((size_t)NLAY*W2T/2);
    us16* gws = (us16*)A((size_t)NLAY*GWSZ/2);
    // node buffers
    us16* xb   = (us16*)A((size_t)NN*HIDN/2);
    us16* wxb  = (us16*)A((size_t)NN*HIDN/2);
    float* xcA = A((size_t)NN*HIDN);
    float* xcB = A((size_t)NN*HIDN);
    float* gd  = A(NN); float* gs = A(NN);
    // CSR + small
    int* cnt     = (int*)A(NN);
    int* rowptr  = (int*)A(NN+1);
    int* cur     = (int*)A(NN);
    int* perm    = (int*)A(NE);
    int* csr_src = (int*)A(NE);
    float* asrc = A(NN*4); float* adst = A(NN*4);
    // messages (CSR-ordered)
    us16* msg = (us16*)A((size_t)NE*HIDN/2);

    const int* ei   = (const int*)d_in[1];
    const int* srcI = ei;
    const int* dstI = ei + NE;

    k_detect<<<1, 1, 0, stream>>>((const u32*)d_in[5], flag);

    ConvTab tab; int cc = 0;
    auto add = [&](int idx, float* dst, int n){ tab.c[cc].s = d_in[idx]; tab.c[cc].d = dst; tab.c[cc].n = n; tab.c[cc].pad = 0; cc++; };
    add(0,  xf,    NN*4);
    add(3,  new_w, 4*HIDN); add(4, neb, HIDN); add(5, neg_, HIDN); add(6, nebeta, HIDN);
    add(12, ecb1, NLAY*HIDN);
    add(13, eclng, NLAY*HIDN);     add(14, eclnb, NLAY*HIDN);
    add(16, ecb2, NLAY*HIDN);
    add(17, ecwa, NLAY*256);       add(18, ecba, NLAY);
    add(20, gasrc, NLAY*HIDN); add(21, gadst, NLAY*HIDN); add(22, gbias, NLAY*HIDN);
    add(23, lng,   NLAY*HIDN); add(24, lnb, NLAY*HIDN);
    add(25, aw1, HIDN*HIDN); add(26, ab1, HIDN); add(27, ag, HIDN); add(28, abeta, HIDN);
    add(29, aw2, HIDN*10);   add(30, ab2, 10);
    add(31, vw1, HIDN*HIDN); add(32, vb1, HIDN); add(33, vg, HIDN); add(34, vbeta, HIDN);
    add(35, vw2, HIDN);      add(36, vb2, 1);
    tab.cnt = cc;
    dim3 cgrid(64, cc);
    k_convert_all<<<cgrid, 256, 0, stream>>>(tab, flag);

    k_prepw<<<(PTOT2+255)/256, 256, 0, stream>>>(d_in[11], d_in[15], d_in[19],
                                                 flag, w1t, w2t, gws);

    hipMemsetAsync(cnt, 0, NN*sizeof(int), stream);
    k_hist<<<(NE+255)/256, 256, 0, stream>>>(dstI, cnt);
    k_scan<<<1, 256, 0, stream>>>(cnt, rowptr);
    hipMemcpyAsync(cur, rowptr, NN*sizeof(int), hipMemcpyDeviceToDevice, stream);
    k_csrfill<<<(NE+255)/256, 256, 0, stream>>>(srcI, dstI, cur, perm, csr_src);

    k_nodeenc<<<NN, 128, 0, stream>>>(xf, new_w, neb, neg_, nebeta, xcA, xb);

    float* curx = xcA; float* nxt = xcB;
    int nblocks64 = (NN + 63) / 64;
    int nblocks4  = (NN + 3) / 4;
    int egrid = 512;
    for (int i = 0; i < NLAY; ++i){
        int maxmode = (i % 2 == 0);

        k_predot<<<nblocks4, 256, 0, stream>>>(curx, ecwa + i*256, ecba + i, gd, gs);

        k_edgeconv_mfma<<<egrid, 256, 0, stream>>>(xb, srcI, dstI,
            w1t + (size_t)i*W1T, w2t + (size_t)i*W2T,
            ecb1 + i*HIDN, eclng + i*HIDN, eclnb + i*HIDN,
            ecb2 + i*HIDN, gd, gs, perm, msg);

        k_gatwx<<<nblocks64, 256, 0, stream>>>(xb, gws + (size_t)i*GWSZ,
            gasrc + i*HIDN, gadst + i*HIDN, wxb, asrc, adst);

        k_node_update<<<nblocks4, 256, 0, stream>>>(rowptr, csr_src, msg, wxb,
            asrc, adst, curx, gbias + i*HIDN, lng + i*HIDN, lnb + i*HIDN,
            nxt, xb, maxmode);

        float* tswap = curx; curx = nxt; nxt = tswap;
    }

    k_heads<<<1, 128, 0, stream>>>(curx, aw1, ab1, ag, abeta, aw2, ab2,
                                   vw1, vb1, vg, vbeta, vw2, vb2, d_out, flag);
}